// Round 2
// baseline (998.657 us; speedup 1.0000x reference)
//
#include <hip/hip_runtime.h>
#include <hip/hip_fp16.h>

#define N_T 256
#define N_B 8192
#define INV2PI 0.15915494309189535f
#define CHUNK 64   // output steps per scan worker
#define WARM  64   // warmup steps (state decays as <=0.73^k via f<=sigmoid(1))

__device__ __forceinline__ unsigned f2h2(float a, float b) {
    __half2 h = __floats2half2_rn(a, b);
    union { __half2 h; unsigned u; } cv; cv.h = h; return cv.u;
}
__device__ __forceinline__ void unpack8(uint4 v, float* a) {
    union { unsigned u; __half2 h; } cv; float2 f;
    cv.u = v.x; f = __half22float2(cv.h); a[0] = f.x; a[1] = f.y;
    cv.u = v.y; f = __half22float2(cv.h); a[2] = f.x; a[3] = f.y;
    cv.u = v.z; f = __half22float2(cv.h); a[4] = f.x; a[5] = f.y;
    cv.u = v.w; f = __half22float2(cv.h); a[6] = f.x; a[7] = f.y;
}
__device__ __forceinline__ float cos_rev(float r) {   // cos(2*pi*r), |r| < 1
    float d; asm("v_cos_f32 %0, %1" : "=v"(d) : "v"(r)); return d;
}
__device__ __forceinline__ float fast_sigmoid(float z) {
    return __builtin_amdgcn_rcpf(1.0f + __expf(-z));
}
__device__ __forceinline__ float fast_tanh(float z) {
    float e = __expf(2.0f * z);
    return 1.0f - 2.0f * __builtin_amdgcn_rcpf(e + 1.0f);
}

// ---------------------------------------------------------------------------
// K1: pre_rev[t][b][w*4+g] = (W_g[w,:32].x + b_g[w] + th_g[w]) / (2*pi), fp16.
// E=4 elements/thread to amortize LDS weight broadcasts over FMAs.
// ---------------------------------------------------------------------------
__global__ __launch_bounds__(256) void qlstm_pre(
    const float* __restrict__ x,
    const float* __restrict__ Wf, const float* __restrict__ bf,
    const float* __restrict__ Wi, const float* __restrict__ bi,
    const float* __restrict__ Wu, const float* __restrict__ bu,
    const float* __restrict__ Wo, const float* __restrict__ bo,
    const float* __restrict__ thf, const float* __restrict__ thi,
    const float* __restrict__ thu, const float* __restrict__ tho,
    uint4* __restrict__ pre)      // (total, 16) fp16 -> 2x uint4 per element
{
    __shared__ float4 sW4[8][16];   // [k][u], u = w*4+g, weights * INV2PI
    __shared__ float  sB[16];
    int tid = threadIdx.x;
    if (tid < 128) {
        int k = tid >> 4, u = tid & 15, w = u >> 2, g = u & 3;
        const float* Wg = (g == 0) ? Wf : (g == 1) ? Wi : (g == 2) ? Wu : Wo;
        const float* p = Wg + w * 36 + k * 4;
        sW4[k][u] = make_float4(p[0] * INV2PI, p[1] * INV2PI,
                                p[2] * INV2PI, p[3] * INV2PI);
    }
    if (tid < 16) {
        int u = tid, w = u >> 2, g = u & 3;
        const float* bg = (g == 0) ? bf : (g == 1) ? bi : (g == 2) ? bu : bo;
        const float* tg = (g == 0) ? thf : (g == 1) ? thi : (g == 2) ? thu : tho;
        sB[u] = (bg[w] + tg[w]) * INV2PI;
    }
    __syncthreads();

    int base = blockIdx.x * 1024 + tid;   // elements base + 256*e, e<4

    float acc[4][16];
#pragma unroll
    for (int e = 0; e < 4; ++e)
#pragma unroll
        for (int u = 0; u < 16; ++u) acc[e][u] = sB[u];

    const float4* xr = (const float4*)x;
#pragma unroll
    for (int k = 0; k < 8; ++k) {
        float4 xe[4];
#pragma unroll
        for (int e = 0; e < 4; ++e)
            xe[e] = xr[(size_t)(base + 256 * e) * 8 + k];
#pragma unroll
        for (int u = 0; u < 16; ++u) {
            float4 wv = sW4[k][u];
#pragma unroll
            for (int e = 0; e < 4; ++e)
                acc[e][u] += wv.x * xe[e].x + wv.y * xe[e].y
                           + wv.z * xe[e].z + wv.w * xe[e].w;
        }
    }

#pragma unroll
    for (int e = 0; e < 4; ++e) {
        uint4 o0, o1;
        o0.x = f2h2(acc[e][0],  acc[e][1]);  o0.y = f2h2(acc[e][2],  acc[e][3]);
        o0.z = f2h2(acc[e][4],  acc[e][5]);  o0.w = f2h2(acc[e][6],  acc[e][7]);
        o1.x = f2h2(acc[e][8],  acc[e][9]);  o1.y = f2h2(acc[e][10], acc[e][11]);
        o1.z = f2h2(acc[e][12], acc[e][13]); o1.w = f2h2(acc[e][14], acc[e][15]);
        size_t p = (size_t)(base + 256 * e) * 2;
        pre[p] = o0; pre[p + 1] = o1;
    }
}

// ---------------------------------------------------------------------------
// K2: 1 lane per (batch, time-chunk) worker. No cross-lane ops at all.
// Chunk k outputs t in [k*CHUNK, (k+1)*CHUNK), warming up from t-WARM with
// h=c=0 (or exact carried state when the warmup start clamps to 0).
// ---------------------------------------------------------------------------
__global__ __launch_bounds__(64) void qlstm_scan(
    const uint4* __restrict__ pre,
    const float* __restrict__ Wf, const float* __restrict__ Wi,
    const float* __restrict__ Wu, const float* __restrict__ Wo,
    const float* __restrict__ Wr, const float* __restrict__ br,
    float4* __restrict__ stacked4, float* __restrict__ regress,
    float* __restrict__ hT, float* __restrict__ cT,
    float* __restrict__ hs, float* __restrict__ cs,
    int steps, int toff, int first, int n_chunks)
{
    int tid   = blockIdx.x * 64 + threadIdx.x;
    int b     = tid & (N_B - 1);
    int chunk = tid >> 13;
    int out_start = chunk * CHUNK;
    if (out_start >= steps) return;
    int out_end = out_start + CHUNK; if (out_end > steps) out_end = steps;
    int t0 = out_start - WARM; if (t0 < 0) t0 = 0;

    float wh[4][4][4];   // [g][w][j], scaled to revolutions
#pragma unroll
    for (int w = 0; w < 4; ++w)
#pragma unroll
        for (int j = 0; j < 4; ++j) {
            wh[0][w][j] = Wf[w * 36 + 32 + j] * INV2PI;
            wh[1][w][j] = Wi[w * 36 + 32 + j] * INV2PI;
            wh[2][w][j] = Wu[w * 36 + 32 + j] * INV2PI;
            wh[3][w][j] = Wo[w * 36 + 32 + j] * INV2PI;
        }
    float wr0 = Wr[0], wr1 = Wr[1], wr2 = Wr[2], wr3 = Wr[3], brv = br[0];

    float h[4] = {0.f, 0.f, 0.f, 0.f}, c[4] = {0.f, 0.f, 0.f, 0.f};
    if (t0 == 0 && !first) {
#pragma unroll
        for (int w = 0; w < 4; ++w) { h[w] = hs[b * 4 + w]; c[w] = cs[b * 4 + w]; }
    }

    // 2-deep prefetch of pre (fp16, 32 B/step = 2x uint4)
    int tl = out_end - 1;
    size_t i0 = ((size_t)t0 * N_B + b) * 2;
    uint4 pa0 = pre[i0], pb0 = pre[i0 + 1];
    int t1 = t0 + 1 > tl ? tl : t0 + 1;
    size_t i1 = ((size_t)t1 * N_B + b) * 2;
    uint4 pa1 = pre[i1], pb1 = pre[i1 + 1];

    for (int t = t0; t < out_end; ++t) {
        int tn = t + 2 > tl ? tl : t + 2;
        size_t ni = ((size_t)tn * N_B + b) * 2;
        uint4 na = pre[ni], nb = pre[ni + 1];

        float a[16];
        unpack8(pa0, a); unpack8(pb0, a + 8);

        float cg[4][4];   // [w][g]
#pragma unroll
        for (int w = 0; w < 4; ++w)
#pragma unroll
            for (int g = 0; g < 4; ++g) {
                float ang = a[w * 4 + g];
#pragma unroll
                for (int j = 0; j < 4; ++j) ang += wh[g][w][j] * h[j];
                cg[w][g] = cos_rev(ang);
            }

        float q[4][4];    // [w][g]
#pragma unroll
        for (int g = 0; g < 4; ++g) {
            float c0 = cg[0][g], c1 = cg[1][g], c2 = cg[2][g], c3 = cg[3][g];
            float t01 = c0 * c1, t012 = t01 * c2, t0123 = t012 * c3;
            float t123 = c1 * (c2 * c3);
            q[0][g] = t123; q[1][g] = t01; q[2][g] = t012; q[3][g] = t0123;
        }

#pragma unroll
        for (int w = 0; w < 4; ++w) {
            float fg = fast_sigmoid(q[w][0]);
            float ig = fast_sigmoid(q[w][1]);
            float gg = fast_tanh(q[w][2]);
            float og = fast_sigmoid(q[w][3]);
            c[w] = fg * c[w] + ig * gg;
            h[w] = og * fast_tanh(c[w]);
        }

        if (t >= out_start) {
            size_t tg = (size_t)(toff + t);
            stacked4[tg * N_B + b] = make_float4(h[0], h[1], h[2], h[3]);
            regress[tg * N_B + b] =
                brv + wr0 * h[0] + wr1 * h[1] + wr2 * h[2] + wr3 * h[3];
        }
        pa0 = pa1; pb0 = pb1; pa1 = na; pb1 = nb;
    }

    if (out_end == steps) {
#pragma unroll
        for (int w = 0; w < 4; ++w) { hs[b * 4 + w] = h[w]; cs[b * 4 + w] = c[w]; }
        if (toff + steps == N_T) {
#pragma unroll
            for (int w = 0; w < 4; ++w) { hT[b * 4 + w] = h[w]; cT[b * 4 + w] = c[w]; }
        }
    }
}

extern "C" void kernel_launch(void* const* d_in, const int* in_sizes, int n_in,
                              void* d_out, int out_size, void* d_ws, size_t ws_size,
                              hipStream_t stream)
{
    (void)in_sizes; (void)n_in; (void)out_size;
    const float* x   = (const float*)d_in[0];
    const float* Wf  = (const float*)d_in[1];
    const float* bf_ = (const float*)d_in[2];
    const float* Wi  = (const float*)d_in[3];
    const float* bi_ = (const float*)d_in[4];
    const float* Wu  = (const float*)d_in[5];
    const float* bu_ = (const float*)d_in[6];
    const float* Wo  = (const float*)d_in[7];
    const float* bo_ = (const float*)d_in[8];
    const float* thf = (const float*)d_in[9];
    const float* thi = (const float*)d_in[10];
    const float* thu = (const float*)d_in[11];
    const float* tho = (const float*)d_in[12];
    const float* Wr  = (const float*)d_in[13];
    const float* br_ = (const float*)d_in[14];

    float* out      = (float*)d_out;
    float4* stacked = (float4*)out;                       // T*B*4 floats
    float* regress  = out + (size_t)N_T * N_B * 4;        // T*B
    float* hT       = regress + (size_t)N_T * N_B;        // B*4
    float* cT       = hT + (size_t)N_B * 4;               // B*4

    size_t stateBytes = (size_t)N_B * 8 * sizeof(float);
    int Tc = N_T;
    while (Tc > 1 && (size_t)Tc * N_B * 32 + stateBytes > ws_size)
        Tc >>= 1;

    uint4* pre = (uint4*)d_ws;
    float* hs  = (float*)((char*)d_ws + (size_t)Tc * N_B * 32);
    float* cs  = hs + (size_t)N_B * 4;

    for (int toff = 0; toff < N_T; toff += Tc) {
        int steps = (N_T - toff < Tc) ? (N_T - toff) : Tc;
        int total = steps * N_B;
        qlstm_pre<<<total / 1024, 256, 0, stream>>>(
            x + (size_t)toff * N_B * 32,
            Wf, bf_, Wi, bi_, Wu, bu_, Wo, bo_,
            thf, thi, thu, tho, pre);
        int n_chunks = (steps + CHUNK - 1) / CHUNK;
        qlstm_scan<<<128 * n_chunks, 64, 0, stream>>>(
            pre, Wf, Wi, Wu, Wo, Wr, br_,
            stacked, regress, hT, cT, hs, cs,
            steps, toff, toff == 0 ? 1 : 0, n_chunks);
    }
}

// Round 3
// 184.478 us; speedup vs baseline: 5.4134x; 5.4134x over previous
//
#include <hip/hip_runtime.h>
#include <hip/hip_fp16.h>

#define N_T 256
#define N_B 8192
#define INV2PI 0.15915494309189535f
#define CHUNK 16   // output steps per scan worker
#define WARM  40   // warmup steps; f<=sigmoid(1)=0.731 => residual ~4e-6

__device__ __forceinline__ unsigned f2h2(float a, float b) {
    __half2 h = __floats2half2_rn(a, b);
    union { __half2 h; unsigned u; } cv; cv.h = h; return cv.u;
}
__device__ __forceinline__ void unpack8(uint4 v, float* a) {
    union { unsigned u; __half2 h; } cv; float2 f;
    cv.u = v.x; f = __half22float2(cv.h); a[0] = f.x; a[1] = f.y;
    cv.u = v.y; f = __half22float2(cv.h); a[2] = f.x; a[3] = f.y;
    cv.u = v.z; f = __half22float2(cv.h); a[4] = f.x; a[5] = f.y;
    cv.u = v.w; f = __half22float2(cv.h); a[6] = f.x; a[7] = f.y;
}
__device__ __forceinline__ float cos_rev(float r) {   // cos(2*pi*r)
    float d; asm("v_cos_f32 %0, %1" : "=v"(d) : "v"(r)); return d;
}
__device__ __forceinline__ float fast_sigmoid(float z) {
    return __builtin_amdgcn_rcpf(1.0f + __expf(-z));
}
__device__ __forceinline__ float fast_tanh(float z) {
    float e = __expf(2.0f * z);
    return 1.0f - 2.0f * __builtin_amdgcn_rcpf(e + 1.0f);
}

// ---------------------------------------------------------------------------
// K1: round-1 structure (E=1, no spills). Output fp16 angles in revolutions:
// pre[t][b][w*4+g] = (W_g[w,:32].x[t,b,:] + b_g[w] + th_g[w]) * INV2PI
// ---------------------------------------------------------------------------
__global__ __launch_bounds__(256) void qlstm_pre(
    const float* __restrict__ x,
    const float* __restrict__ Wf, const float* __restrict__ bf,
    const float* __restrict__ Wi, const float* __restrict__ bi,
    const float* __restrict__ Wu, const float* __restrict__ bu,
    const float* __restrict__ Wo, const float* __restrict__ bo,
    const float* __restrict__ thf, const float* __restrict__ thi,
    const float* __restrict__ thu, const float* __restrict__ tho,
    uint4* __restrict__ pre, int total)
{
    __shared__ float sW[16][32];   // [u][j] scaled by INV2PI, u = w*4+g
    __shared__ float sB[16];
    int tid = threadIdx.x;
    for (int k = tid; k < 512; k += 256) {
        int u = k >> 5, j = k & 31;
        int w = u >> 2, g = u & 3;
        const float* Wg = (g == 0) ? Wf : (g == 1) ? Wi : (g == 2) ? Wu : Wo;
        sW[u][j] = Wg[w * 36 + j] * INV2PI;
    }
    if (tid < 16) {
        int u = tid, w = u >> 2, g = u & 3;
        const float* bg = (g == 0) ? bf : (g == 1) ? bi : (g == 2) ? bu : bo;
        const float* tg = (g == 0) ? thf : (g == 1) ? thi : (g == 2) ? thu : tho;
        sB[u] = (bg[w] + tg[w]) * INV2PI;
    }
    __syncthreads();

    int idx = blockIdx.x * 256 + tid;
    if (idx >= total) return;

    const float4* xr = (const float4*)(x + (size_t)idx * 32);
    float4 xv[8];
#pragma unroll
    for (int k = 0; k < 8; ++k) xv[k] = xr[k];

    float acc[16];
#pragma unroll
    for (int u = 0; u < 16; ++u) {
        float a = sB[u];
        const float4* wr = (const float4*)(&sW[u][0]);
#pragma unroll
        for (int k = 0; k < 8; ++k) {
            float4 wv = wr[k];   // wave-uniform address -> LDS broadcast
            a += wv.x * xv[k].x + wv.y * xv[k].y + wv.z * xv[k].z + wv.w * xv[k].w;
        }
        acc[u] = a;
    }

    uint4 o0, o1;
    o0.x = f2h2(acc[0],  acc[1]);  o0.y = f2h2(acc[2],  acc[3]);
    o0.z = f2h2(acc[4],  acc[5]);  o0.w = f2h2(acc[6],  acc[7]);
    o1.x = f2h2(acc[8],  acc[9]);  o1.y = f2h2(acc[10], acc[11]);
    o1.z = f2h2(acc[12], acc[13]); o1.w = f2h2(acc[14], acc[15]);
    size_t p = (size_t)idx * 2;
    pre[p] = o0; pre[p + 1] = o1;
}

// ---------------------------------------------------------------------------
// K2: 1 lane per (batch, time-chunk) worker; no cross-lane ops.
// Chunk k outputs t in [k*CHUNK, k*CHUNK+CHUNK), warming up from t-WARM
// (exact carried/zero state when the warmup start clamps to 0).
// ---------------------------------------------------------------------------
__global__ __launch_bounds__(64) void qlstm_scan(
    const uint4* __restrict__ pre,
    const float* __restrict__ Wf, const float* __restrict__ Wi,
    const float* __restrict__ Wu, const float* __restrict__ Wo,
    const float* __restrict__ Wr, const float* __restrict__ br,
    float4* __restrict__ stacked4, float* __restrict__ regress,
    float* __restrict__ hT, float* __restrict__ cT,
    float* __restrict__ hs, float* __restrict__ cs,
    int steps, int toff, int first)
{
    int tid   = blockIdx.x * 64 + threadIdx.x;
    int b     = tid & (N_B - 1);
    int chunk = tid >> 13;
    int out_start = chunk * CHUNK;
    if (out_start >= steps) return;
    int out_end = out_start + CHUNK; if (out_end > steps) out_end = steps;
    int t0 = out_start - WARM; if (t0 < 0) t0 = 0;

    float wh[4][4][4];   // [g][w][j], scaled to revolutions
#pragma unroll
    for (int w = 0; w < 4; ++w)
#pragma unroll
        for (int j = 0; j < 4; ++j) {
            wh[0][w][j] = Wf[w * 36 + 32 + j] * INV2PI;
            wh[1][w][j] = Wi[w * 36 + 32 + j] * INV2PI;
            wh[2][w][j] = Wu[w * 36 + 32 + j] * INV2PI;
            wh[3][w][j] = Wo[w * 36 + 32 + j] * INV2PI;
        }
    float wr0 = Wr[0], wr1 = Wr[1], wr2 = Wr[2], wr3 = Wr[3], brv = br[0];

    float h[4] = {0.f, 0.f, 0.f, 0.f}, c[4] = {0.f, 0.f, 0.f, 0.f};
    if (t0 == 0 && !first) {
#pragma unroll
        for (int w = 0; w < 4; ++w) { h[w] = hs[b * 4 + w]; c[w] = cs[b * 4 + w]; }
    }

    int tl = out_end - 1;
    size_t i0 = ((size_t)t0 * N_B + b) * 2;
    uint4 pa0 = pre[i0], pb0 = pre[i0 + 1];
    int t1 = t0 + 1 > tl ? tl : t0 + 1;
    size_t i1 = ((size_t)t1 * N_B + b) * 2;
    uint4 pa1 = pre[i1], pb1 = pre[i1 + 1];

    for (int t = t0; t < out_end; ++t) {
        int tn = t + 2 > tl ? tl : t + 2;
        size_t ni = ((size_t)tn * N_B + b) * 2;
        uint4 na = pre[ni], nb = pre[ni + 1];

        float a[16];
        unpack8(pa0, a); unpack8(pb0, a + 8);

        float cg[4][4];   // [w][g]
#pragma unroll
        for (int w = 0; w < 4; ++w)
#pragma unroll
            for (int g = 0; g < 4; ++g) {
                float ang = a[w * 4 + g];
#pragma unroll
                for (int j = 0; j < 4; ++j) ang += wh[g][w][j] * h[j];
                cg[w][g] = cos_rev(ang);
            }

        float q[4][4];    // [w][g]
#pragma unroll
        for (int g = 0; g < 4; ++g) {
            float c0 = cg[0][g], c1 = cg[1][g], c2 = cg[2][g], c3 = cg[3][g];
            float t01 = c0 * c1, t012 = t01 * c2, t0123 = t012 * c3;
            float t123 = c1 * (c2 * c3);
            q[0][g] = t123; q[1][g] = t01; q[2][g] = t012; q[3][g] = t0123;
        }

#pragma unroll
        for (int w = 0; w < 4; ++w) {
            float fg = fast_sigmoid(q[w][0]);
            float ig = fast_sigmoid(q[w][1]);
            float gg = fast_tanh(q[w][2]);
            float og = fast_sigmoid(q[w][3]);
            c[w] = fg * c[w] + ig * gg;
            h[w] = og * fast_tanh(c[w]);
        }

        if (t >= out_start) {
            size_t tg = (size_t)(toff + t);
            stacked4[tg * N_B + b] = make_float4(h[0], h[1], h[2], h[3]);
            regress[tg * N_B + b] =
                brv + wr0 * h[0] + wr1 * h[1] + wr2 * h[2] + wr3 * h[3];
        }
        pa0 = pa1; pb0 = pb1; pa1 = na; pb1 = nb;
    }

    if (out_end == steps) {
#pragma unroll
        for (int w = 0; w < 4; ++w) { hs[b * 4 + w] = h[w]; cs[b * 4 + w] = c[w]; }
        if (toff + steps == N_T) {
#pragma unroll
            for (int w = 0; w < 4; ++w) { hT[b * 4 + w] = h[w]; cT[b * 4 + w] = c[w]; }
        }
    }
}

extern "C" void kernel_launch(void* const* d_in, const int* in_sizes, int n_in,
                              void* d_out, int out_size, void* d_ws, size_t ws_size,
                              hipStream_t stream)
{
    (void)in_sizes; (void)n_in; (void)out_size;
    const float* x   = (const float*)d_in[0];
    const float* Wf  = (const float*)d_in[1];
    const float* bf_ = (const float*)d_in[2];
    const float* Wi  = (const float*)d_in[3];
    const float* bi_ = (const float*)d_in[4];
    const float* Wu  = (const float*)d_in[5];
    const float* bu_ = (const float*)d_in[6];
    const float* Wo  = (const float*)d_in[7];
    const float* bo_ = (const float*)d_in[8];
    const float* thf = (const float*)d_in[9];
    const float* thi = (const float*)d_in[10];
    const float* thu = (const float*)d_in[11];
    const float* tho = (const float*)d_in[12];
    const float* Wr  = (const float*)d_in[13];
    const float* br_ = (const float*)d_in[14];

    float* out      = (float*)d_out;
    float4* stacked = (float4*)out;                       // T*B*4 floats
    float* regress  = out + (size_t)N_T * N_B * 4;        // T*B
    float* hT       = regress + (size_t)N_T * N_B;        // B*4
    float* cT       = hT + (size_t)N_B * 4;               // B*4

    size_t stateBytes = (size_t)N_B * 8 * sizeof(float);
    int Tc = N_T;
    while (Tc > 1 && (size_t)Tc * N_B * 32 + stateBytes > ws_size)
        Tc >>= 1;

    uint4* pre = (uint4*)d_ws;
    float* hs  = (float*)((char*)d_ws + (size_t)Tc * N_B * 32);
    float* cs  = hs + (size_t)N_B * 4;

    for (int toff = 0; toff < N_T; toff += Tc) {
        int steps = (N_T - toff < Tc) ? (N_T - toff) : Tc;
        int total = steps * N_B;
        qlstm_pre<<<(total + 255) / 256, 256, 0, stream>>>(
            x + (size_t)toff * N_B * 32,
            Wf, bf_, Wi, bi_, Wu, bu_, Wo, bo_,
            thf, thi, thu, tho, pre, total);
        int n_chunks = (steps + CHUNK - 1) / CHUNK;
        qlstm_scan<<<128 * n_chunks, 64, 0, stream>>>(
            pre, Wf, Wi, Wu, Wo, Wr, br_,
            stacked, regress, hT, cT, hs, cs,
            steps, toff, toff == 0 ? 1 : 0);
    }
}

// Round 4
// 134.207 us; speedup vs baseline: 7.4412x; 1.3746x over previous
//
#include <hip/hip_runtime.h>
#include <hip/hip_fp16.h>

#define N_T 256
#define N_B 8192
#define INV2PI 0.15915494309189535f
#define CHUNK 16   // output steps per scan worker
#define WARM  40   // warmup steps; f<=sigmoid(1)=0.731 => residual ~4e-6

typedef _Float16 half8_t __attribute__((ext_vector_type(8)));
typedef float f32x4_t __attribute__((ext_vector_type(4)));

__device__ __forceinline__ void unpack8(uint4 v, float* a) {
    union { unsigned u; __half2 h; } cv; float2 f;
    cv.u = v.x; f = __half22float2(cv.h); a[0] = f.x; a[1] = f.y;
    cv.u = v.y; f = __half22float2(cv.h); a[2] = f.x; a[3] = f.y;
    cv.u = v.z; f = __half22float2(cv.h); a[4] = f.x; a[5] = f.y;
    cv.u = v.w; f = __half22float2(cv.h); a[6] = f.x; a[7] = f.y;
}
__device__ __forceinline__ float cos_rev(float r) {   // cos(2*pi*r)
    float d; asm("v_cos_f32 %0, %1" : "=v"(d) : "v"(r)); return d;
}
__device__ __forceinline__ float fast_sigmoid(float z) {
    return __builtin_amdgcn_rcpf(1.0f + __expf(-z));
}
__device__ __forceinline__ float fast_tanh(float z) {
    float e = __expf(2.0f * z);
    return 1.0f - 2.0f * __builtin_amdgcn_rcpf(e + 1.0f);
}

// ---------------------------------------------------------------------------
// K1 (MFMA): pre[elem][u] = (W_g[w,:32].x[elem,:] + b_g[w] + th_g[w])*INV2PI
// as fp16, u = w*4+g.  One mfma_f32_16x16x32_f16 per 16 elements:
//   A = Wrev (16x32), held in registers per lane (row = lane&15)
//   B = X^T fragment: lane reads x[grp16 + (lane&15)][ (lane>>4)*8 + j ]
//   C[row=u][col=elem]: lane holds u = (lane>>4)*4+r for elem = lane&15
// No LDS at all -> DS pipe (round-3 bottleneck) eliminated.
// ---------------------------------------------------------------------------
__global__ __launch_bounds__(256) void qlstm_pre_mfma(
    const float* __restrict__ x,
    const float* __restrict__ Wf, const float* __restrict__ bf,
    const float* __restrict__ Wi, const float* __restrict__ bi,
    const float* __restrict__ Wu, const float* __restrict__ bu,
    const float* __restrict__ Wo, const float* __restrict__ bo,
    const float* __restrict__ thf, const float* __restrict__ thi,
    const float* __restrict__ thu, const float* __restrict__ tho,
    char* __restrict__ pre, int ngroups)   // ngroups = total/16
{
    int lane = threadIdx.x & 63;
    int wid  = (blockIdx.x * blockDim.x + threadIdx.x) >> 6;
    int nwaves = (gridDim.x * blockDim.x) >> 6;
    int e  = lane & 15;    // element-in-group == C col
    int kq = lane >> 4;    // 0..3

    // A fragment: Wrev[u=e][k=kq*8+j]
    half8_t afrag;
    {
        int u = e, w = u >> 2, g = u & 3;
        const float* Wg = (g == 0) ? Wf : (g == 1) ? Wi : (g == 2) ? Wu : Wo;
#pragma unroll
        for (int j = 0; j < 8; ++j)
            afrag[j] = (_Float16)(Wg[w * 36 + kq * 8 + j] * INV2PI);
    }
    // bias+theta for the 4 C rows this lane owns: ur = kq*4 + r
    float bias[4];
#pragma unroll
    for (int r = 0; r < 4; ++r) {
        int ur = kq * 4 + r, w = ur >> 2, g = ur & 3;
        const float* bg = (g == 0) ? bf : (g == 1) ? bi : (g == 2) ? bu : bo;
        const float* tg = (g == 0) ? thf : (g == 1) ? thi : (g == 2) ? thu : tho;
        bias[r] = (bg[w] + tg[w]) * INV2PI;
    }

    const float4* xr = (const float4*)x;
    for (int grp = wid; grp < ngroups; grp += nwaves) {
        int elem = grp * 16 + e;
        size_t fi = (size_t)elem * 8 + kq * 2;
        float4 xa = xr[fi];
        float4 xb = xr[fi + 1];
        half8_t bfrag;
        bfrag[0] = (_Float16)xa.x; bfrag[1] = (_Float16)xa.y;
        bfrag[2] = (_Float16)xa.z; bfrag[3] = (_Float16)xa.w;
        bfrag[4] = (_Float16)xb.x; bfrag[5] = (_Float16)xb.y;
        bfrag[6] = (_Float16)xb.z; bfrag[7] = (_Float16)xb.w;

        f32x4_t acc = {0.f, 0.f, 0.f, 0.f};
        acc = __builtin_amdgcn_mfma_f32_16x16x32_f16(afrag, bfrag, acc, 0, 0, 0);

        union { _Float16 h[4]; uint2 u2; } ov;
#pragma unroll
        for (int r = 0; r < 4; ++r)
            ov.h[r] = (_Float16)(acc[r] + bias[r]);
        *(uint2*)(pre + (size_t)elem * 32 + kq * 8) = ov.u2;
    }
}

// ---------------------------------------------------------------------------
// K2: 1 lane per (batch, time-chunk) worker; no cross-lane ops. (unchanged)
// ---------------------------------------------------------------------------
__global__ __launch_bounds__(64) void qlstm_scan(
    const uint4* __restrict__ pre,
    const float* __restrict__ Wf, const float* __restrict__ Wi,
    const float* __restrict__ Wu, const float* __restrict__ Wo,
    const float* __restrict__ Wr, const float* __restrict__ br,
    float4* __restrict__ stacked4, float* __restrict__ regress,
    float* __restrict__ hT, float* __restrict__ cT,
    float* __restrict__ hs, float* __restrict__ cs,
    int steps, int toff, int first)
{
    int tid   = blockIdx.x * 64 + threadIdx.x;
    int b     = tid & (N_B - 1);
    int chunk = tid >> 13;
    int out_start = chunk * CHUNK;
    if (out_start >= steps) return;
    int out_end = out_start + CHUNK; if (out_end > steps) out_end = steps;
    int t0 = out_start - WARM; if (t0 < 0) t0 = 0;

    float wh[4][4][4];   // [g][w][j], scaled to revolutions
#pragma unroll
    for (int w = 0; w < 4; ++w)
#pragma unroll
        for (int j = 0; j < 4; ++j) {
            wh[0][w][j] = Wf[w * 36 + 32 + j] * INV2PI;
            wh[1][w][j] = Wi[w * 36 + 32 + j] * INV2PI;
            wh[2][w][j] = Wu[w * 36 + 32 + j] * INV2PI;
            wh[3][w][j] = Wo[w * 36 + 32 + j] * INV2PI;
        }
    float wr0 = Wr[0], wr1 = Wr[1], wr2 = Wr[2], wr3 = Wr[3], brv = br[0];

    float h[4] = {0.f, 0.f, 0.f, 0.f}, c[4] = {0.f, 0.f, 0.f, 0.f};
    if (t0 == 0 && !first) {
#pragma unroll
        for (int w = 0; w < 4; ++w) { h[w] = hs[b * 4 + w]; c[w] = cs[b * 4 + w]; }
    }

    int tl = out_end - 1;
    size_t i0 = ((size_t)t0 * N_B + b) * 2;
    uint4 pa0 = pre[i0], pb0 = pre[i0 + 1];
    int t1 = t0 + 1 > tl ? tl : t0 + 1;
    size_t i1 = ((size_t)t1 * N_B + b) * 2;
    uint4 pa1 = pre[i1], pb1 = pre[i1 + 1];

    for (int t = t0; t < out_end; ++t) {
        int tn = t + 2 > tl ? tl : t + 2;
        size_t ni = ((size_t)tn * N_B + b) * 2;
        uint4 na = pre[ni], nb = pre[ni + 1];

        float a[16];
        unpack8(pa0, a); unpack8(pb0, a + 8);

        float cg[4][4];   // [w][g]
#pragma unroll
        for (int w = 0; w < 4; ++w)
#pragma unroll
            for (int g = 0; g < 4; ++g) {
                float ang = a[w * 4 + g];
#pragma unroll
                for (int j = 0; j < 4; ++j) ang += wh[g][w][j] * h[j];
                cg[w][g] = cos_rev(ang);
            }

        float q[4][4];    // [w][g]
#pragma unroll
        for (int g = 0; g < 4; ++g) {
            float c0 = cg[0][g], c1 = cg[1][g], c2 = cg[2][g], c3 = cg[3][g];
            float t01 = c0 * c1, t012 = t01 * c2, t0123 = t012 * c3;
            float t123 = c1 * (c2 * c3);
            q[0][g] = t123; q[1][g] = t01; q[2][g] = t012; q[3][g] = t0123;
        }

#pragma unroll
        for (int w = 0; w < 4; ++w) {
            float fg = fast_sigmoid(q[w][0]);
            float ig = fast_sigmoid(q[w][1]);
            float gg = fast_tanh(q[w][2]);
            float og = fast_sigmoid(q[w][3]);
            c[w] = fg * c[w] + ig * gg;
            h[w] = og * fast_tanh(c[w]);
        }

        if (t >= out_start) {
            size_t tg = (size_t)(toff + t);
            stacked4[tg * N_B + b] = make_float4(h[0], h[1], h[2], h[3]);
            regress[tg * N_B + b] =
                brv + wr0 * h[0] + wr1 * h[1] + wr2 * h[2] + wr3 * h[3];
        }
        pa0 = pa1; pb0 = pb1; pa1 = na; pb1 = nb;
    }

    if (out_end == steps) {
#pragma unroll
        for (int w = 0; w < 4; ++w) { hs[b * 4 + w] = h[w]; cs[b * 4 + w] = c[w]; }
        if (toff + steps == N_T) {
#pragma unroll
            for (int w = 0; w < 4; ++w) { hT[b * 4 + w] = h[w]; cT[b * 4 + w] = c[w]; }
        }
    }
}

extern "C" void kernel_launch(void* const* d_in, const int* in_sizes, int n_in,
                              void* d_out, int out_size, void* d_ws, size_t ws_size,
                              hipStream_t stream)
{
    (void)in_sizes; (void)n_in; (void)out_size;
    const float* x   = (const float*)d_in[0];
    const float* Wf  = (const float*)d_in[1];
    const float* bf_ = (const float*)d_in[2];
    const float* Wi  = (const float*)d_in[3];
    const float* bi_ = (const float*)d_in[4];
    const float* Wu  = (const float*)d_in[5];
    const float* bu_ = (const float*)d_in[6];
    const float* Wo  = (const float*)d_in[7];
    const float* bo_ = (const float*)d_in[8];
    const float* thf = (const float*)d_in[9];
    const float* thi = (const float*)d_in[10];
    const float* thu = (const float*)d_in[11];
    const float* tho = (const float*)d_in[12];
    const float* Wr  = (const float*)d_in[13];
    const float* br_ = (const float*)d_in[14];

    float* out      = (float*)d_out;
    float4* stacked = (float4*)out;                       // T*B*4 floats
    float* regress  = out + (size_t)N_T * N_B * 4;        // T*B
    float* hT       = regress + (size_t)N_T * N_B;        // B*4
    float* cT       = hT + (size_t)N_B * 4;               // B*4

    size_t stateBytes = (size_t)N_B * 8 * sizeof(float);
    int Tc = N_T;
    while (Tc > 1 && (size_t)Tc * N_B * 32 + stateBytes > ws_size)
        Tc >>= 1;

    char*  pre = (char*)d_ws;
    float* hs  = (float*)((char*)d_ws + (size_t)Tc * N_B * 32);
    float* cs  = hs + (size_t)N_B * 4;

    for (int toff = 0; toff < N_T; toff += Tc) {
        int steps = (N_T - toff < Tc) ? (N_T - toff) : Tc;
        int total = steps * N_B;
        int ngroups = total / 16;
        qlstm_pre_mfma<<<1024, 256, 0, stream>>>(
            x + (size_t)toff * N_B * 32,
            Wf, bf_, Wi, bi_, Wu, bu_, Wo, bo_,
            thf, thi, thu, tho, pre, ngroups);
        int n_chunks = (steps + CHUNK - 1) / CHUNK;
        qlstm_scan<<<128 * n_chunks, 64, 0, stream>>>(
            (const uint4*)pre, Wf, Wi, Wu, Wo, Wr, br_,
            stacked, regress, hT, cT, hs, cs,
            steps, toff, toff == 0 ? 1 : 0);
    }
}

// Round 5
// 129.814 us; speedup vs baseline: 7.6930x; 1.0338x over previous
//
#include <hip/hip_runtime.h>
#include <hip/hip_fp16.h>

#define N_T 256
#define N_B 8192
#define INV2PI 0.15915494309189535f
#define CHUNK 16   // output steps per scan worker
#define WARM  40   // warmup steps; f<=sigmoid(1)=0.731 => residual ~4e-6

typedef _Float16 half8_t __attribute__((ext_vector_type(8)));
typedef float f32x4_t __attribute__((ext_vector_type(4)));

__device__ __forceinline__ void unpack8(uint4 v, float* a) {
    union { unsigned u; __half2 h; } cv; float2 f;
    cv.u = v.x; f = __half22float2(cv.h); a[0] = f.x; a[1] = f.y;
    cv.u = v.y; f = __half22float2(cv.h); a[2] = f.x; a[3] = f.y;
    cv.u = v.z; f = __half22float2(cv.h); a[4] = f.x; a[5] = f.y;
    cv.u = v.w; f = __half22float2(cv.h); a[6] = f.x; a[7] = f.y;
}
__device__ __forceinline__ float cos_rev(float r) {   // cos(2*pi*r)
    float d; asm("v_cos_f32 %0, %1" : "=v"(d) : "v"(r)); return d;
}
// sigmoid on [-1,1]: 0.5 + (1/2)tanh(x/2), odd Taylor deg-7, err ~2.1e-5
__device__ __forceinline__ float sig_p(float x) {
    float u = x * x;
    float p = fmaf(u, -2.108135e-4f, 2.0833333e-3f);
    p = fmaf(u, p, -2.0833333e-2f);
    p = fmaf(u, p, 0.25f);
    return fmaf(x, p, 0.5f);
}
// tanh on [-2.2,2.2]: CF Pade x*(105+10u)/(105+45u+u^2), err<=8e-4 (5e-6 @|x|<=1)
__device__ __forceinline__ float tanh_p(float x) {
    float u = x * x;
    float d = fmaf(u, u + 45.0f, 105.0f);
    float n = x * fmaf(u, 10.0f, 105.0f);
    return n * __builtin_amdgcn_rcpf(d);
}

// ---------------------------------------------------------------------------
// K1 (MFMA): pre[elem][u] = (W_g[w,:32].x[elem,:] + b_g[w] + th_g[w])*INV2PI
// as fp16, u = w*4+g. One mfma_f32_16x16x32_f16 per 16 elements; no LDS.
// ---------------------------------------------------------------------------
__global__ __launch_bounds__(256) void qlstm_pre_mfma(
    const float* __restrict__ x,
    const float* __restrict__ Wf, const float* __restrict__ bf,
    const float* __restrict__ Wi, const float* __restrict__ bi,
    const float* __restrict__ Wu, const float* __restrict__ bu,
    const float* __restrict__ Wo, const float* __restrict__ bo,
    const float* __restrict__ thf, const float* __restrict__ thi,
    const float* __restrict__ thu, const float* __restrict__ tho,
    char* __restrict__ pre, int ngroups)
{
    int lane = threadIdx.x & 63;
    int wid  = (blockIdx.x * blockDim.x + threadIdx.x) >> 6;
    int nwaves = (gridDim.x * blockDim.x) >> 6;
    int e  = lane & 15;
    int kq = lane >> 4;

    half8_t afrag;
    {
        int u = e, w = u >> 2, g = u & 3;
        const float* Wg = (g == 0) ? Wf : (g == 1) ? Wi : (g == 2) ? Wu : Wo;
#pragma unroll
        for (int j = 0; j < 8; ++j)
            afrag[j] = (_Float16)(Wg[w * 36 + kq * 8 + j] * INV2PI);
    }
    float bias[4];
#pragma unroll
    for (int r = 0; r < 4; ++r) {
        int ur = kq * 4 + r, w = ur >> 2, g = ur & 3;
        const float* bg = (g == 0) ? bf : (g == 1) ? bi : (g == 2) ? bu : bo;
        const float* tg = (g == 0) ? thf : (g == 1) ? thi : (g == 2) ? thu : tho;
        bias[r] = (bg[w] + tg[w]) * INV2PI;
    }

    const float4* xr = (const float4*)x;
    for (int grp = wid; grp < ngroups; grp += nwaves) {
        int elem = grp * 16 + e;
        size_t fi = (size_t)elem * 8 + kq * 2;
        float4 xa = xr[fi];
        float4 xb = xr[fi + 1];
        half8_t bfrag;
        bfrag[0] = (_Float16)xa.x; bfrag[1] = (_Float16)xa.y;
        bfrag[2] = (_Float16)xa.z; bfrag[3] = (_Float16)xa.w;
        bfrag[4] = (_Float16)xb.x; bfrag[5] = (_Float16)xb.y;
        bfrag[6] = (_Float16)xb.z; bfrag[7] = (_Float16)xb.w;

        f32x4_t acc = {0.f, 0.f, 0.f, 0.f};
        acc = __builtin_amdgcn_mfma_f32_16x16x32_f16(afrag, bfrag, acc, 0, 0, 0);

        union { _Float16 h[4]; uint2 u2; } ov;
#pragma unroll
        for (int r = 0; r < 4; ++r)
            ov.h[r] = (_Float16)(acc[r] + bias[r]);
        *(uint2*)(pre + (size_t)elem * 32 + kq * 8) = ov.u2;
    }
}

// ---------------------------------------------------------------------------
// K2: 1 lane per (batch, time-chunk) worker; no cross-lane ops, no exp.
// ---------------------------------------------------------------------------
__global__ __launch_bounds__(256) void qlstm_scan(
    const uint4* __restrict__ pre,
    const float* __restrict__ Wf, const float* __restrict__ Wi,
    const float* __restrict__ Wu, const float* __restrict__ Wo,
    const float* __restrict__ Wr, const float* __restrict__ br,
    float4* __restrict__ stacked4, float* __restrict__ regress,
    float* __restrict__ hT, float* __restrict__ cT,
    float* __restrict__ hs, float* __restrict__ cs,
    int steps, int toff, int first)
{
    int tid   = blockIdx.x * 256 + threadIdx.x;
    int b     = tid & (N_B - 1);
    int chunk = tid >> 13;
    int out_start = chunk * CHUNK;
    if (out_start >= steps) return;
    int out_end = out_start + CHUNK; if (out_end > steps) out_end = steps;
    int t0 = out_start - WARM; if (t0 < 0) t0 = 0;

    float wh[4][4][4];   // [g][w][j], scaled to revolutions
#pragma unroll
    for (int w = 0; w < 4; ++w)
#pragma unroll
        for (int j = 0; j < 4; ++j) {
            wh[0][w][j] = Wf[w * 36 + 32 + j] * INV2PI;
            wh[1][w][j] = Wi[w * 36 + 32 + j] * INV2PI;
            wh[2][w][j] = Wu[w * 36 + 32 + j] * INV2PI;
            wh[3][w][j] = Wo[w * 36 + 32 + j] * INV2PI;
        }
    float wr0 = Wr[0], wr1 = Wr[1], wr2 = Wr[2], wr3 = Wr[3], brv = br[0];

    float h[4] = {0.f, 0.f, 0.f, 0.f}, c[4] = {0.f, 0.f, 0.f, 0.f};
    if (t0 == 0 && !first) {
#pragma unroll
        for (int w = 0; w < 4; ++w) { h[w] = hs[b * 4 + w]; c[w] = cs[b * 4 + w]; }
    }

    int tl = out_end - 1;
    size_t i0 = ((size_t)t0 * N_B + b) * 2;
    uint4 pa0 = pre[i0], pb0 = pre[i0 + 1];
    int t1 = t0 + 1 > tl ? tl : t0 + 1;
    size_t i1 = ((size_t)t1 * N_B + b) * 2;
    uint4 pa1 = pre[i1], pb1 = pre[i1 + 1];

    for (int t = t0; t < out_end; ++t) {
        int tn = t + 2 > tl ? tl : t + 2;
        size_t ni = ((size_t)tn * N_B + b) * 2;
        uint4 na = pre[ni], nb = pre[ni + 1];

        float a[16];
        unpack8(pa0, a); unpack8(pb0, a + 8);

        float cg[4][4];   // [w][g]
#pragma unroll
        for (int w = 0; w < 4; ++w)
#pragma unroll
            for (int g = 0; g < 4; ++g) {
                float ang = a[w * 4 + g];
#pragma unroll
                for (int j = 0; j < 4; ++j) ang += wh[g][w][j] * h[j];
                cg[w][g] = cos_rev(ang);
            }

        float q[4][4];    // [w][g]
#pragma unroll
        for (int g = 0; g < 4; ++g) {
            float c0 = cg[0][g], c1 = cg[1][g], c2 = cg[2][g], c3 = cg[3][g];
            float t01 = c0 * c1, t012 = t01 * c2, t0123 = t012 * c3;
            float t123 = c1 * (c2 * c3);
            q[0][g] = t123; q[1][g] = t01; q[2][g] = t012; q[3][g] = t0123;
        }

#pragma unroll
        for (int w = 0; w < 4; ++w) {
            float fg = sig_p(q[w][0]);
            float ig = sig_p(q[w][1]);
            float gg = tanh_p(q[w][2]);
            float og = sig_p(q[w][3]);
            c[w] = fmaf(fg, c[w], ig * gg);
            h[w] = og * tanh_p(c[w]);
        }

        if (t >= out_start) {
            size_t tg = (size_t)(toff + t);
            stacked4[tg * N_B + b] = make_float4(h[0], h[1], h[2], h[3]);
            regress[tg * N_B + b] =
                brv + wr0 * h[0] + wr1 * h[1] + wr2 * h[2] + wr3 * h[3];
        }
        pa0 = pa1; pb0 = pb1; pa1 = na; pb1 = nb;
    }

    if (out_end == steps) {
#pragma unroll
        for (int w = 0; w < 4; ++w) { hs[b * 4 + w] = h[w]; cs[b * 4 + w] = c[w]; }
        if (toff + steps == N_T) {
#pragma unroll
            for (int w = 0; w < 4; ++w) { hT[b * 4 + w] = h[w]; cT[b * 4 + w] = c[w]; }
        }
    }
}

extern "C" void kernel_launch(void* const* d_in, const int* in_sizes, int n_in,
                              void* d_out, int out_size, void* d_ws, size_t ws_size,
                              hipStream_t stream)
{
    (void)in_sizes; (void)n_in; (void)out_size;
    const float* x   = (const float*)d_in[0];
    const float* Wf  = (const float*)d_in[1];
    const float* bf_ = (const float*)d_in[2];
    const float* Wi  = (const float*)d_in[3];
    const float* bi_ = (const float*)d_in[4];
    const float* Wu  = (const float*)d_in[5];
    const float* bu_ = (const float*)d_in[6];
    const float* Wo  = (const float*)d_in[7];
    const float* bo_ = (const float*)d_in[8];
    const float* thf = (const float*)d_in[9];
    const float* thi = (const float*)d_in[10];
    const float* thu = (const float*)d_in[11];
    const float* tho = (const float*)d_in[12];
    const float* Wr  = (const float*)d_in[13];
    const float* br_ = (const float*)d_in[14];

    float* out      = (float*)d_out;
    float4* stacked = (float4*)out;                       // T*B*4 floats
    float* regress  = out + (size_t)N_T * N_B * 4;        // T*B
    float* hT       = regress + (size_t)N_T * N_B;        // B*4
    float* cT       = hT + (size_t)N_B * 4;               // B*4

    size_t stateBytes = (size_t)N_B * 8 * sizeof(float);
    int Tc = N_T;
    while (Tc > 1 && (size_t)Tc * N_B * 32 + stateBytes > ws_size)
        Tc >>= 1;

    char*  pre = (char*)d_ws;
    float* hs  = (float*)((char*)d_ws + (size_t)Tc * N_B * 32);
    float* cs  = hs + (size_t)N_B * 4;

    for (int toff = 0; toff < N_T; toff += Tc) {
        int steps = (N_T - toff < Tc) ? (N_T - toff) : Tc;
        int total = steps * N_B;
        int ngroups = total / 16;
        qlstm_pre_mfma<<<1024, 256, 0, stream>>>(
            x + (size_t)toff * N_B * 32,
            Wf, bf_, Wi, bi_, Wu, bu_, Wo, bo_,
            thf, thi, thu, tho, pre, ngroups);
        int n_chunks = (steps + CHUNK - 1) / CHUNK;
        int nthreads = N_B * n_chunks;
        qlstm_scan<<<nthreads / 256, 256, 0, stream>>>(
            (const uint4*)pre, Wf, Wi, Wu, Wo, Wr, br_,
            stacked, regress, hT, cT, hs, cs,
            steps, toff, toff == 0 ? 1 : 0);
    }
}